// Round 7
// baseline (451.183 us; speedup 1.0000x reference)
//
#include <hip/hip_runtime.h>
#include <math.h>

#define N_NODES 50000
#define N_EDGES 800000
#define N_GRAPHS 512
#define SLOPE 0.2f
#define CAP 48   // bucket capacity; degrees ~Poisson(16), P(deg>48)~1e-11
static constexpr float EPS_BN = 1e-5f;
static constexpr unsigned MAXOFF = (N_NODES - 1) * 64;  // clamp for garbage-slot gathers

typedef float v2f __attribute__((ext_vector_type(2)));

// ---------------- fused bucket-scatter + layer-0 transform (known-good t9) ----------
// ~57 us = atomic-chain floor at max TLP (tested EPT 1/2/4); accepted.

__global__ __launch_bounds__(256) void scatter_t9_kernel(
    const int* __restrict__ src, const int* __restrict__ dst,
    const float* __restrict__ ea,
    int* __restrict__ cnt, float4* __restrict__ rec,
    const float* __restrict__ x,
    const float* __restrict__ Wl0, const float* __restrict__ bl0,
    const float* __restrict__ Wr0, const float* __restrict__ br0,
    float* __restrict__ xl, float* __restrict__ xr) {
    int t = threadIdx.x;
    int e = blockIdx.x * 256 + t;
    if (e < N_EDGES) {
        int d = dst[e];
        int pos = atomicAdd(&cnt[d], 1);
        if (pos < CAP)
            rec[(size_t)d * CAP + pos] = make_float4(__int_as_float(src[e] * 64),
                                                     ea[e * 3 + 0], ea[e * 3 + 1], ea[e * 3 + 2]);
    }

    int w = t >> 6;
    int k = t & 63;
    v2f wlr[9];
#pragma unroll
    for (int j = 0; j < 9; j++) wlr[j] = (v2f){Wl0[j * 64 + k], Wr0[j * 64 + k]};
    v2f bias = {bl0[k], br0[k]};
    const int NW = gridDim.x * 4;
    for (int n = blockIdx.x * 4 + w; n < N_NODES; n += NW) {
        int un = __builtin_amdgcn_readfirstlane(n);
        const float* __restrict__ hrow = x + (size_t)un * 9;
        float hb[9];
#pragma unroll
        for (int j = 0; j < 9; j++) hb[j] = hrow[j];
        v2f acc = bias;
#pragma unroll
        for (int j = 0; j < 9; j++)
            acc = __builtin_elementwise_fma((v2f){hb[j], hb[j]}, wlr[j], acc);
        xl[(size_t)un * 64 + k] = acc.x;
        xr[(size_t)un * 64 + k] = acc.y;
    }
}

// ---------------- fused GATv2 + NEXT-LAYER transform epilogue ----------------------
// gat (2-deep edge pipeline) writes h rows to LDS hT (transposed); every 8 nodes a
// per-wave 8x128 mini-GEMM vs LDS-staged Wln/Wrn produces xln/xrn directly — the
// standalone transform kernel disappears. The transform(i+1)->gat(i) dependency is
// per-node pointwise, so no grid sync is needed; the next launch syncs the gathers.
// Lane map for epilogue: q = mat*2 + jh (mat: 0=xl 1=xr; jh: j-half), cols r*4..+3.

#define EDGE_T(rX, xXa, xXb, accX)                                        \
    {                                                                     \
        v2f tXa = xXa + xra, tXb = xXb + xrb;                             \
        tXa = __builtin_elementwise_fma((v2f){rX.y, rX.y}, we0a, tXa);    \
        tXb = __builtin_elementwise_fma((v2f){rX.y, rX.y}, we0b, tXb);    \
        tXa = __builtin_elementwise_fma((v2f){rX.z, rX.z}, we1a, tXa);    \
        tXb = __builtin_elementwise_fma((v2f){rX.z, rX.z}, we1b, tXb);    \
        tXa = __builtin_elementwise_fma((v2f){rX.w, rX.w}, we2a, tXa);    \
        tXb = __builtin_elementwise_fma((v2f){rX.w, rX.w}, we2b, tXb);    \
        tXa = __builtin_elementwise_max(tXa, tXa * SLOPE);                \
        tXb = __builtin_elementwise_max(tXb, tXb * SLOPE);                \
        v2f dX = ata * tXa;                                               \
        dX = __builtin_elementwise_fma(atb, tXb, dX);                     \
        accX = dX.x + dX.y;                                               \
    }

#define MMROW(kk, hv)                                                              \
    acc[kk][0] = __builtin_elementwise_fma((v2f){hv, hv}, w0, acc[kk][0]);         \
    acc[kk][1] = __builtin_elementwise_fma((v2f){hv, hv}, w1, acc[kk][1]);

__global__ __launch_bounds__(256) void gat_fusedT_kernel(
    const float* __restrict__ xl, const float* __restrict__ xr,
    const float4* __restrict__ recP, const int* __restrict__ cnt,
    const float* __restrict__ We, const float* __restrict__ att,
    const float* __restrict__ bo,
    const float* __restrict__ bn_g, const float* __restrict__ bn_b,
    const float* __restrict__ bn_m, const float* __restrict__ bn_v,
    const float* __restrict__ Wln, const float* __restrict__ bln,
    const float* __restrict__ Wrn, const float* __restrict__ brn,
    float* __restrict__ xln, float* __restrict__ xrn) {
    __shared__ float sW[2][64][68];   // next-layer Wl/Wr, pad 68 (34816 B)
    __shared__ float hT[4][64][12];   // per-wave h^T rows, pad 12: 16B-aligned reads (12288 B)
    int t = threadIdx.x;
    int w = t >> 6;
    int lane = t & 63;
    int q = lane >> 4;
    int r = lane & 15;
    int k4 = r * 4;

    // stage next-layer weights once per block
    for (int i = t; i < 2048; i += 256) {
        int mt = i >> 10;
        int j  = (i >> 4) & 63;
        int fc = i & 15;
        const float* Wsrc = mt ? Wrn : Wln;
        *((float4*)&sW[mt][j][fc * 4]) = *((const float4*)(Wsrc + j * 64 + fc * 4));
    }
    __syncthreads();

    float4 we0 = *(const float4*)(We + 0 * 64 + k4);
    float4 we1 = *(const float4*)(We + 64 + k4);
    float4 we2 = *(const float4*)(We + 128 + k4);
    float4 at4 = *(const float4*)(att + k4);
    v2f we0a = {we0.x, we0.y}, we0b = {we0.z, we0.w};
    v2f we1a = {we1.x, we1.y}, we1b = {we1.z, we1.w};
    v2f we2a = {we2.x, we2.y}, we2b = {we2.z, we2.w};
    v2f ata  = {at4.x, at4.y}, atb  = {at4.z, at4.w};
    float4 bo4 = *(const float4*)(bo + k4);
    float4 g4  = *(const float4*)(bn_g + k4);
    float4 b4  = *(const float4*)(bn_b + k4);
    float4 m4  = *(const float4*)(bn_m + k4);
    float4 v4  = *(const float4*)(bn_v + k4);
    float4 S, C;
    S.x = g4.x / sqrtf(v4.x + EPS_BN);  C.x = (bo4.x - m4.x) * S.x + b4.x;
    S.y = g4.y / sqrtf(v4.y + EPS_BN);  C.y = (bo4.y - m4.y) * S.y + b4.y;
    S.z = g4.z / sqrtf(v4.z + EPS_BN);  C.z = (bo4.z - m4.z) * S.z + b4.z;
    S.w = g4.w / sqrtf(v4.w + EPS_BN);  C.w = (bo4.w - m4.w) * S.w + b4.w;

    const int mat = q >> 1, jh = q & 1;

    const int NW = gridDim.x * 4;
    for (int b0 = blockIdx.x * 4 + w; b0 < N_NODES; b0 += NW * 8) {
        int kmax = 0;
        // ---- gat for up to 8 nodes; h rows -> hT (transposed) ----
#pragma unroll 1
        for (int kk = 0; kk < 8; kk++) {
            int nn = b0 + kk * NW;
            if (nn >= N_NODES) break;
            kmax = kk + 1;
            int n = __builtin_amdgcn_readfirstlane(nn);
            int beg = n * CAP;
            int end = beg + min(cnt[n], CAP);
            float4 xq = *(const float4*)(xr + (size_t)n * 64 + k4);
            v2f xra = {xq.x, xq.y}, xrb = {xq.z, xq.w};

            // prologue: all rec loads unguarded (recP has 16 slack records);
            // garbage offsets clamped, garbage lanes masked at exp (select).
            float4 cA0 = recP[beg + q];
            float4 cB0 = recP[beg + 4 + q];
            float4 cA1 = recP[beg + 8 + q];
            float4 cB1 = recP[beg + 12 + q];
            bool wA0 = (beg + q) < end,      wB0 = (beg + 4 + q) < end;
            bool wA1 = (beg + 8 + q) < end,  wB1 = (beg + 12 + q) < end;
            float4 gA0 = *(const float4*)(xl + (min((unsigned)__float_as_int(cA0.x), MAXOFF) + k4));
            float4 gB0 = *(const float4*)(xl + (min((unsigned)__float_as_int(cB0.x), MAXOFF) + k4));

            v2f oAa = {0.f, 0.f}, oAb = {0.f, 0.f};
            v2f oBa = {0.f, 0.f}, oBb = {0.f, 0.f};
            float zA = 0.f, zB = 0.f;

            int c = beg;
            while (c < end) {
                float4 gA1 = *(const float4*)(xl + (min((unsigned)__float_as_int(cA1.x), MAXOFF) + k4));
                float4 gB1 = *(const float4*)(xl + (min((unsigned)__float_as_int(cB1.x), MAXOFF) + k4));
                float4 cA2 = recP[c + 16 + q];
                float4 cB2 = recP[c + 20 + q];
                bool wA2 = (c + 16 + q) < end, wB2 = (c + 20 + q) < end;

                v2f xAa = {gA0.x, gA0.y}, xAb = {gA0.z, gA0.w};
                v2f xBa = {gB0.x, gB0.y}, xBb = {gB0.z, gB0.w};

                float accA, accB;
                EDGE_T(cA0, xAa, xAb, accA);
                EDGE_T(cB0, xBa, xBb, accB);

                accA += __shfl_xor(accA, 1, 64);  accB += __shfl_xor(accB, 1, 64);
                accA += __shfl_xor(accA, 2, 64);  accB += __shfl_xor(accB, 2, 64);
                accA += __shfl_xor(accA, 4, 64);  accB += __shfl_xor(accB, 4, 64);
                accA += __shfl_xor(accA, 8, 64);  accB += __shfl_xor(accB, 8, 64);

                float peA = wA0 ? __expf(accA) : 0.f;
                float peB = wB0 ? __expf(accB) : 0.f;
                v2f pAv = {peA, peA}, pBv = {peB, peB};
                oAa = __builtin_elementwise_fma(pAv, xAa, oAa);
                oAb = __builtin_elementwise_fma(pAv, xAb, oAb);
                oBa = __builtin_elementwise_fma(pBv, xBa, oBa);
                oBb = __builtin_elementwise_fma(pBv, xBb, oBb);
                zA += peA; zB += peB;

                cA0 = cA1; cB0 = cB1; wA0 = wA1; wB0 = wB1;
                cA1 = cA2; cB1 = cB2; wA1 = wA2; wB1 = wB2;
                gA0 = gA1; gB0 = gB1;
                c += 8;
            }

            v2f oa = oAa + oBa, ob = oAb + oBb;
            float z = zA + zB;
            float4 o = make_float4(oa.x, oa.y, ob.x, ob.y);
            o.x += __shfl_xor(o.x, 16, 64); o.x += __shfl_xor(o.x, 32, 64);
            o.y += __shfl_xor(o.y, 16, 64); o.y += __shfl_xor(o.y, 32, 64);
            o.z += __shfl_xor(o.z, 16, 64); o.z += __shfl_xor(o.z, 32, 64);
            o.w += __shfl_xor(o.w, 16, 64); o.w += __shfl_xor(o.w, 32, 64);
            z += __shfl_xor(z, 16, 64); z += __shfl_xor(z, 32, 64);

            if (q == 0) {
                float zi = 1.0f / fmaxf(z, 1e-16f);
                hT[w][k4 + 0][kk] = fmaxf(fmaf(o.x * zi, S.x, C.x), 0.f);
                hT[w][k4 + 1][kk] = fmaxf(fmaf(o.y * zi, S.y, C.y), 0.f);
                hT[w][k4 + 2][kk] = fmaxf(fmaf(o.z * zi, S.z, C.z), 0.f);
                hT[w][k4 + 3][kk] = fmaxf(fmaf(o.w * zi, S.w, C.w), 0.f);
            }
        }

        // wave-local visibility of hT (same wave wrote it)
        asm volatile("s_waitcnt lgkmcnt(0)" ::: "memory");

        // ---- per-wave 8x128 mini-GEMM: xln/xrn rows for the batch ----
        v2f acc[8][2];
#pragma unroll
        for (int kk = 0; kk < 8; kk++) { acc[kk][0] = (v2f){0.f, 0.f}; acc[kk][1] = (v2f){0.f, 0.f}; }
#pragma unroll 4
        for (int j16 = 0; j16 < 32; j16++) {
            int j = jh * 32 + j16;
            float4 wv  = *(const float4*)&sW[mat][j][k4];
            float4 h03 = *(const float4*)&hT[w][j][0];
            float4 h47 = *(const float4*)&hT[w][j][4];
            v2f w0 = {wv.x, wv.y}, w1 = {wv.z, wv.w};
            MMROW(0, h03.x); MMROW(1, h03.y); MMROW(2, h03.z); MMROW(3, h03.w);
            MMROW(4, h47.x); MMROW(5, h47.y); MMROW(6, h47.z); MMROW(7, h47.w);
        }
#pragma unroll
        for (int kk = 0; kk < 8; kk++) {
            acc[kk][0].x += __shfl_xor(acc[kk][0].x, 16, 64);
            acc[kk][0].y += __shfl_xor(acc[kk][0].y, 16, 64);
            acc[kk][1].x += __shfl_xor(acc[kk][1].x, 16, 64);
            acc[kk][1].y += __shfl_xor(acc[kk][1].y, 16, 64);
        }
        if (jh == 0) {
            float* dstp = mat ? xrn : xln;
            float4 be = mat ? *(const float4*)(brn + k4) : *(const float4*)(bln + k4);
#pragma unroll
            for (int kk = 0; kk < 8; kk++) {
                if (kk < kmax) {
                    int nn = b0 + kk * NW;
                    float4 o4 = make_float4(acc[kk][0].x + be.x, acc[kk][0].y + be.y,
                                            acc[kk][1].x + be.z, acc[kk][1].y + be.w);
                    *((float4*)(dstp + (size_t)nn * 64 + k4)) = o4;
                }
            }
        }
    }
}

// ---------------- plain fused GATv2 (last layer, writes h) -------------------------

__global__ __launch_bounds__(256) void gat_fused12_kernel(
    const float* __restrict__ xl, const float* __restrict__ xr,
    const float4* __restrict__ recP, const int* __restrict__ cnt,
    const float* __restrict__ We, const float* __restrict__ att,
    const float* __restrict__ bo,
    const float* __restrict__ bn_g, const float* __restrict__ bn_b,
    const float* __restrict__ bn_m, const float* __restrict__ bn_v,
    float* __restrict__ hout) {
    int t = threadIdx.x;
    int w = t >> 6;
    int lane = t & 63;
    int q = lane >> 4;
    int r = lane & 15;
    int k4 = r * 4;

    float4 we0 = *(const float4*)(We + 0 * 64 + k4);
    float4 we1 = *(const float4*)(We + 64 + k4);
    float4 we2 = *(const float4*)(We + 128 + k4);
    float4 at4 = *(const float4*)(att + k4);
    v2f we0a = {we0.x, we0.y}, we0b = {we0.z, we0.w};
    v2f we1a = {we1.x, we1.y}, we1b = {we1.z, we1.w};
    v2f we2a = {we2.x, we2.y}, we2b = {we2.z, we2.w};
    v2f ata  = {at4.x, at4.y}, atb  = {at4.z, at4.w};
    float4 bo4 = *(const float4*)(bo + k4);
    float4 g4  = *(const float4*)(bn_g + k4);
    float4 b4  = *(const float4*)(bn_b + k4);
    float4 m4  = *(const float4*)(bn_m + k4);
    float4 v4  = *(const float4*)(bn_v + k4);
    float4 S, C;
    S.x = g4.x / sqrtf(v4.x + EPS_BN);  C.x = (bo4.x - m4.x) * S.x + b4.x;
    S.y = g4.y / sqrtf(v4.y + EPS_BN);  C.y = (bo4.y - m4.y) * S.y + b4.y;
    S.z = g4.z / sqrtf(v4.z + EPS_BN);  C.z = (bo4.z - m4.z) * S.z + b4.z;
    S.w = g4.w / sqrtf(v4.w + EPS_BN);  C.w = (bo4.w - m4.w) * S.w + b4.w;

    const int NW = gridDim.x * 4;
    for (int n0 = blockIdx.x * 4 + w; n0 < N_NODES; n0 += NW) {
        int n = __builtin_amdgcn_readfirstlane(n0);
        float4 xq = *(const float4*)(xr + (size_t)n * 64 + k4);
        v2f xra = {xq.x, xq.y}, xrb = {xq.z, xq.w};
        int beg = n * CAP;
        int end = beg + min(cnt[n], CAP);

        float4 cA0 = recP[beg + q];
        float4 cB0 = recP[beg + 4 + q];
        float4 cA1 = recP[beg + 8 + q];
        float4 cB1 = recP[beg + 12 + q];
        bool wA0 = (beg + q) < end,      wB0 = (beg + 4 + q) < end;
        bool wA1 = (beg + 8 + q) < end,  wB1 = (beg + 12 + q) < end;
        float4 gA0 = *(const float4*)(xl + (min((unsigned)__float_as_int(cA0.x), MAXOFF) + k4));
        float4 gB0 = *(const float4*)(xl + (min((unsigned)__float_as_int(cB0.x), MAXOFF) + k4));

        v2f oAa = {0.f, 0.f}, oAb = {0.f, 0.f};
        v2f oBa = {0.f, 0.f}, oBb = {0.f, 0.f};
        float zA = 0.f, zB = 0.f;

        int c = beg;
        while (c < end) {
            float4 gA1 = *(const float4*)(xl + (min((unsigned)__float_as_int(cA1.x), MAXOFF) + k4));
            float4 gB1 = *(const float4*)(xl + (min((unsigned)__float_as_int(cB1.x), MAXOFF) + k4));
            float4 cA2 = recP[c + 16 + q];
            float4 cB2 = recP[c + 20 + q];
            bool wA2 = (c + 16 + q) < end, wB2 = (c + 20 + q) < end;

            v2f xAa = {gA0.x, gA0.y}, xAb = {gA0.z, gA0.w};
            v2f xBa = {gB0.x, gB0.y}, xBb = {gB0.z, gB0.w};

            float accA, accB;
            EDGE_T(cA0, xAa, xAb, accA);
            EDGE_T(cB0, xBa, xBb, accB);

            accA += __shfl_xor(accA, 1, 64);  accB += __shfl_xor(accB, 1, 64);
            accA += __shfl_xor(accA, 2, 64);  accB += __shfl_xor(accB, 2, 64);
            accA += __shfl_xor(accA, 4, 64);  accB += __shfl_xor(accB, 4, 64);
            accA += __shfl_xor(accA, 8, 64);  accB += __shfl_xor(accB, 8, 64);

            float peA = wA0 ? __expf(accA) : 0.f;
            float peB = wB0 ? __expf(accB) : 0.f;
            v2f pAv = {peA, peA}, pBv = {peB, peB};
            oAa = __builtin_elementwise_fma(pAv, xAa, oAa);
            oAb = __builtin_elementwise_fma(pAv, xAb, oAb);
            oBa = __builtin_elementwise_fma(pBv, xBa, oBa);
            oBb = __builtin_elementwise_fma(pBv, xBb, oBb);
            zA += peA; zB += peB;

            cA0 = cA1; cB0 = cB1; wA0 = wA1; wB0 = wB1;
            cA1 = cA2; cB1 = cB2; wA1 = wA2; wB1 = wB2;
            gA0 = gA1; gB0 = gB1;
            c += 8;
        }

        v2f oa = oAa + oBa, ob = oAb + oBb;
        float z = zA + zB;
        float4 o = make_float4(oa.x, oa.y, ob.x, ob.y);
        o.x += __shfl_xor(o.x, 16, 64); o.x += __shfl_xor(o.x, 32, 64);
        o.y += __shfl_xor(o.y, 16, 64); o.y += __shfl_xor(o.y, 32, 64);
        o.z += __shfl_xor(o.z, 16, 64); o.z += __shfl_xor(o.z, 32, 64);
        o.w += __shfl_xor(o.w, 16, 64); o.w += __shfl_xor(o.w, 32, 64);
        z += __shfl_xor(z, 16, 64); z += __shfl_xor(z, 32, 64);

        if (q == 0) {
            float zi = 1.0f / fmaxf(z, 1e-16f);
            float4 res;
            res.x = fmaxf(fmaf(o.x * zi, S.x, C.x), 0.f);
            res.y = fmaxf(fmaf(o.y * zi, S.y, C.y), 0.f);
            res.z = fmaxf(fmaf(o.z * zi, S.z, C.z), 0.f);
            res.w = fmaxf(fmaf(o.w * zi, S.w, C.w), 0.f);
            *(float4*)(hout + (size_t)n * 64 + k4) = res;
        }
    }
}

// ---------------- readout: 4 waves/block, LDS cross-wave reduce ----------------

__global__ __launch_bounds__(256) void pool_all2_kernel(
    const float* __restrict__ h, const int* __restrict__ batch,
    const float* __restrict__ Wjk, const float* __restrict__ bjk,
    const float* __restrict__ Whead, const float* __restrict__ bhead,
    float* __restrict__ out) {
    __shared__ float red[4][64];
    int g = blockIdx.x;
    int t = threadIdx.x;
    int k = t & 63;
    int w = t >> 6;
    int lo = 0, hi = N_NODES;
    while (lo < hi) { int mid = (lo + hi) >> 1; if (batch[mid] < g) lo = mid + 1; else hi = mid; }
    int s = lo;
    hi = N_NODES;
    while (lo < hi) { int mid = (lo + hi) >> 1; if (batch[mid] < g + 1) lo = mid + 1; else hi = mid; }
    int e = lo;

    float acc = 0.f;
    for (int n = s + w; n < e; n += 4) acc += h[(size_t)n * 64 + k];
    red[w][k] = acc;
    __syncthreads();

    if (w == 0) {
        acc = (red[0][k] + red[1][k]) + (red[2][k] + red[3][k]);
        float wc = 0.f;
        for (int j = 0; j < 64; j++) wc = fmaf(Wjk[k * 64 + j], Whead[j], wc);
        float bc = bjk[k] * Whead[k];
        for (int off = 32; off > 0; off >>= 1) bc += __shfl_xor(bc, off, 64);
        float cntf = (float)(e - s);
        acc /= fmaxf(cntf, 1.0f);
        float v = acc * wc;
        for (int off = 32; off > 0; off >>= 1) v += __shfl_xor(v, off, 64);
        if (k == 0) out[g] = v + bc + bhead[0];
    }
}

// ---------------- launch ----------------

extern "C" void kernel_launch(void* const* d_in, const int* in_sizes, int n_in,
                              void* d_out, int out_size, void* d_ws, size_t ws_size,
                              hipStream_t stream) {
    const float* x     = (const float*)d_in[0];
    const float* ea    = (const float*)d_in[1];
    const float* Wl0   = (const float*)d_in[2];
    const float* Wr0   = (const float*)d_in[3];
    const float* bl0   = (const float*)d_in[4];
    const float* br0   = (const float*)d_in[5];
    const float* We0   = (const float*)d_in[6];
    const float* att0  = (const float*)d_in[7];
    const float* bo0   = (const float*)d_in[8];
    const float* Wl    = (const float*)d_in[9];
    const float* Wr    = (const float*)d_in[10];
    const float* bl    = (const float*)d_in[11];
    const float* br    = (const float*)d_in[12];
    const float* We    = (const float*)d_in[13];
    const float* att   = (const float*)d_in[14];
    const float* bo    = (const float*)d_in[15];
    const float* bn_g  = (const float*)d_in[16];
    const float* bn_b  = (const float*)d_in[17];
    const float* bn_m  = (const float*)d_in[18];
    const float* bn_v  = (const float*)d_in[19];
    const float* Wjk   = (const float*)d_in[20];
    const float* bjk   = (const float*)d_in[21];
    const float* Whead = (const float*)d_in[22];
    const float* bhead = (const float*)d_in[23];
    const int* edge_index = (const int*)d_in[24];
    const int* batch      = (const int*)d_in[25];

    const int* srcIdx = edge_index;            // edge_index[0]
    const int* dstIdx = edge_index + N_EDGES;  // edge_index[1]

    char* ws = (char*)d_ws;
    size_t off = 0;
    auto alloc = [&](size_t bytes) -> void* {
        void* p = ws + off;
        off += (bytes + 255) & ~(size_t)255;
        return p;
    };
    float* hbuf    = (float*)alloc((size_t)N_NODES * 64 * 4);
    float* xlA     = (float*)alloc((size_t)N_NODES * 64 * 4);
    float* xrA     = (float*)alloc((size_t)N_NODES * 64 * 4);
    float* xlB     = (float*)alloc((size_t)N_NODES * 64 * 4);
    float* xrB     = (float*)alloc((size_t)N_NODES * 64 * 4);
    int*   cnt     = (int*)alloc((size_t)N_NODES * 4);
    float4* recP   = (float4*)alloc(((size_t)N_NODES * CAP + 16) * 16);  // +16 slack records

    // ---- fused bucket build + layer-0 transform ----
    hipMemsetAsync(cnt, 0, (size_t)N_NODES * 4, stream);
    scatter_t9_kernel<<<(N_EDGES + 255) / 256, 256, 0, stream>>>(
        srcIdx, dstIdx, ea, cnt, recP, x, Wl0, bl0, Wr0, br0, xlA, xrA);

    const int GBF = 768;     // gatT grid: 3 blocks/CU resident (47KB LDS), grid-stride
    const int GB  = 2048;    // last-layer gat grid

    // ---- layers 0..3: gat + fused next-layer transform ----
    // layer 0 reads xlA -> writes xlB; then alternate.
    gat_fusedT_kernel<<<GBF, 256, 0, stream>>>(xlA, xrA, recP, cnt,
        We0, att0, bo0, bn_g, bn_b, bn_m, bn_v,
        Wl, bl, Wr, br, xlB, xrB);
    for (int i = 1; i < 4; i++) {
        const float* xin  = (i & 1) ? xlB : xlA;
        const float* xrin = (i & 1) ? xrB : xrA;
        float* xout  = (i & 1) ? xlA : xlB;
        float* xrout = (i & 1) ? xrA : xrB;
        gat_fusedT_kernel<<<GBF, 256, 0, stream>>>(xin, xrin, recP, cnt,
            We + (size_t)(i - 1) * 3 * 64, att + (size_t)(i - 1) * 64,
            bo + (size_t)(i - 1) * 64,
            bn_g + (size_t)i * 64, bn_b + (size_t)i * 64,
            bn_m + (size_t)i * 64, bn_v + (size_t)i * 64,
            Wl + (size_t)i * 64 * 64, bl + (size_t)i * 64,
            Wr + (size_t)i * 64 * 64, br + (size_t)i * 64,
            xout, xrout);
    }

    // ---- layer 4: plain gat -> h ----
    gat_fused12_kernel<<<GB, 256, 0, stream>>>(xlA, xrA, recP, cnt,
        We + (size_t)3 * 3 * 64, att + (size_t)3 * 64, bo + (size_t)3 * 64,
        bn_g + (size_t)4 * 64, bn_b + (size_t)4 * 64,
        bn_m + (size_t)4 * 64, bn_v + (size_t)4 * 64,
        hbuf);

    // ---- readout ----
    pool_all2_kernel<<<N_GRAPHS, 256, 0, stream>>>(hbuf, batch, Wjk, bjk, Whead, bhead,
                                                   (float*)d_out);
}